// Round 1
// baseline (5043.014 us; speedup 1.0000x reference)
//
#include <hip/hip_runtime.h>
#include <math.h>

#define BN_SC 0.9999950000374997f
#define BN2   0.9999900000999990f
#define LOGC  (-9.210340371976184f)

// ---- ws float offsets ----
#define OFF_S      0L         // 1280*200
#define OFF_ADJB   256000L    // 1400 uints
#define OFF_P1     257408L    // 224
#define OFF_Q1     257664L    // 224
#define OFF_BEFF1  257920L    // 32
#define OFF_BEFF2  257952L    // 64
#define OFF_C12    258016L    // 2
#define OFF_W2L    258304L    // 28672  [c][dt][o]
#define OFF_SPWT   286976L    // 204800 [vj][d]
#define OFF_WINT   491776L    // 12288  [c][i]
#define OFF_OWT    504064L    // 4096   [e][d]
#define OFF_F1T    508160L    // 8192   [c][r]
#define OFF_F2T    516352L    // 8192   [r][c]
#define OFF_FEATST 524544L    // 1024
#define OFF_XS0    525568L    // 81920
#define OFF_TN1O   607488L    // 4096
#define OFF_A      611584L    // 256000
#define OFF_G      867584L    // 102400
#define OFF_RS     969984L    // 256000
#define OFF_TV     1225984L   // 321600
#define OFF_Y      1547584L   // 4096000
#define OFF_G2R    5643584L   // 16384000
// total 22,027,584 floats = 88.1 MB

__device__ inline float wsum(float v){ for(int o=32;o>0;o>>=1) v += __shfl_xor(v,o); return v; }
__device__ inline float wmax(float v){ for(int o=32;o>0;o>>=1) v = fmaxf(v,__shfl_xor(v,o)); return v; }

// ---------------- prep 1: spwT transpose + Weff2 + beff2 ----------------
__global__ void kprep1(const float* __restrict__ sp_w,
                       const float* __restrict__ fw2,
                       const float* __restrict__ w3, const float* __restrict__ w5, const float* __restrict__ w7,
                       const float* __restrict__ b3, const float* __restrict__ b5, const float* __restrict__ b7,
                       const float* __restrict__ fb2,
                       float* __restrict__ W)
{
    int bid = blockIdx.x, tid = threadIdx.x;
    if (bid < 64) {
        int d = bid;
        for (int vj = tid; vj < 3200; vj += 256)
            W[OFF_SPWT + (long)vj*64 + d] = sp_w[d*3200 + vj];
    } else {
        int o = bid - 64;
        for (int idx = tid; idx < 448; idx += 256) {
            int c = idx / 7, dt = idx % 7;
            float acc = 0.f;
            for (int cp = 0; cp < 64; cp++) {
                float f3 = fw2[o*192 + cp], f5 = fw2[o*192 + 64 + cp], f7 = fw2[o*192 + 128 + cp];
                if (dt >= 2 && dt <= 4) acc += f3 * w3[(cp*64 + c)*3 + (dt-2)];
                if (dt >= 1 && dt <= 5) acc += f5 * w5[(cp*64 + c)*5 + (dt-1)];
                acc += f7 * w7[(cp*64 + c)*7 + dt];
            }
            W[OFF_W2L + (long)(c*7+dt)*64 + o] = acc * BN2;
        }
        if (tid == 0) {
            float acc = fb2[o];
            for (int cp = 0; cp < 64; cp++)
                acc += (fw2[o*192+cp]*b3[cp] + fw2[o*192+64+cp]*b5[cp] + fw2[o*192+128+cp]*b7[cp]) * BN_SC;
            W[OFF_BEFF2 + o] = acc;
        }
    }
}

// ---------------- prep 2: c1/c2, P1/Q1, beff1, adj bitmask, transposes ----------------
__global__ void kprep2(const float* __restrict__ g1W, const float* __restrict__ g1a,
                       const float* __restrict__ w3, const float* __restrict__ w5, const float* __restrict__ w7,
                       const float* __restrict__ b3, const float* __restrict__ b5, const float* __restrict__ b7,
                       const float* __restrict__ fw1, const float* __restrict__ fb1,
                       const float* __restrict__ adj,
                       const float* __restrict__ inw, const float* __restrict__ ow,
                       const float* __restrict__ f1, const float* __restrict__ f2,
                       float* __restrict__ W)
{
    __shared__ float weff[7168]; // [o][c][dt] 32*32*7
    int tid = threadIdx.x;
    if (tid == 0) {
        float c1 = 0.f, c2 = 0.f;
        for (int f = 0; f < 32; f++){ c1 += g1W[f]*g1a[f]; c2 += g1W[f]*g1a[32+f]; }
        W[OFF_C12] = c1; W[OFF_C12+1] = c2;
    }
    for (int idx = tid; idx < 7168; idx += 256) {
        int o = idx/224, rem = idx%224, c = rem/7, dt = rem%7;
        float acc = 0.f;
        for (int cp = 0; cp < 32; cp++) {
            float f3 = fw1[o*96+cp], f5 = fw1[o*96+32+cp], f7 = fw1[o*96+64+cp];
            if (dt >= 2 && dt <= 4) acc += f3*w3[(cp*32+c)*3+(dt-2)];
            if (dt >= 1 && dt <= 5) acc += f5*w5[(cp*32+c)*5+(dt-1)];
            acc += f7*w7[(cp*32+c)*7+dt];
        }
        weff[idx] = acc * BN2;
    }
    __syncthreads();
    for (int idx = tid; idx < 224; idx += 256) {
        int o = idx/7, dt = idx%7;
        float p = 0.f, q = 0.f;
        for (int c = 0; c < 32; c++){
            float wv = weff[o*224 + c*7 + dt];
            float w0 = g1W[c];
            p += wv * fmaxf(w0, 0.f);
            q += wv * fmaxf(-w0, 0.f);
        }
        W[OFF_P1 + idx] = p; W[OFF_Q1 + idx] = q;
    }
    if (tid < 32) {
        int o = tid;
        float acc = fb1[o];
        for (int cp = 0; cp < 32; cp++)
            acc += (fw1[o*96+cp]*b3[cp] + fw1[o*96+32+cp]*b5[cp] + fw1[o*96+64+cp]*b7[cp]) * BN_SC;
        W[OFF_BEFF1+o] = acc;
    }
    unsigned* adjb = (unsigned*)(W + OFF_ADJB);
    for (int idx = tid; idx < 1400; idx += 256) {
        int v = idx/7, qw = idx%7;
        unsigned bits = 0;
        for (int k = 0; k < 32; k++){ int j = qw*32+k; if (j < 200 && adj[v*200+j] > 0.f) bits |= (1u<<k); }
        adjb[idx] = bits;
    }
    for (int idx = tid; idx < 12288; idx += 256){ int i = idx%192; int c = idx/192; W[OFF_WINT+idx] = inw[i*64+c]; }
    for (int idx = tid; idx < 4096;  idx += 256){ int d = idx%64;  int e = idx/64;  W[OFF_OWT+idx]  = ow[d*64+e]; }
    for (int idx = tid; idx < 8192;  idx += 256){ int r = idx%128; int c = idx/128; W[OFF_F1T+idx]  = f1[r*64+c]; }
    for (int idx = tid; idx < 8192;  idx += 256){ int c = idx%64;  int r = idx/64;  W[OFF_F2T+idx]  = f2[c*128+r]; }
}

// ---------------- GAT1 (scalar-feature collapse): s[bt][v] ----------------
__global__ void __launch_bounds__(256) kgat1(const float* __restrict__ x, float* __restrict__ W)
{
    __shared__ float xrow[200];
    __shared__ unsigned adjb[1400];
    int bt = blockIdx.x, tid = threadIdx.x;
    int lane = tid & 63, wv = tid >> 6;
    const unsigned* gadj = (const unsigned*)(W + OFF_ADJB);
    for (int i = tid; i < 200; i += 256) xrow[i] = x[bt*200+i];
    for (int i = tid; i < 1400; i += 256) adjb[i] = gadj[i];
    __syncthreads();
    float c1 = W[OFF_C12], c2 = W[OFF_C12+1];
    for (int v = wv; v < 200; v += 4) {
        float xv = xrow[v];
        float m = -3.4e38f;
        for (int j = lane; j < 200; j += 64) {
            if ((adjb[v*7 + (j>>5)] >> (j&31)) & 1u) {
                float z = c1*xv + c2*xrow[j];
                z = z > 0.f ? z : 0.2f*z;
                m = fmaxf(m, z);
            }
        }
        m = wmax(m);
        float den = 0.f, num = 0.f;
        for (int j = lane; j < 200; j += 64) {
            if ((adjb[v*7 + (j>>5)] >> (j&31)) & 1u) {
                float z = c1*xv + c2*xrow[j];
                z = z > 0.f ? z : 0.2f*z;
                float p = __expf(z - m);
                den += p; num += p * xrow[j];
            }
        }
        den = wsum(den); num = wsum(num);
        if (lane == 0) W[OFF_S + bt*200 + v] = num / den;
    }
}

// ---------------- GAT2 with conv1 fused in (per (b,t) block) ----------------
__global__ void __launch_bounds__(256) kgat2(const float* __restrict__ g2W, const float* __restrict__ g2a,
                                             float* __restrict__ W)
{
    extern __shared__ float sm[];
    float* sp7  = sm;            // 1400
    float* sn7  = sm + 1400;     // 1400
    float* hh   = sm + 2800;     // 6400  [v][c32]
    float* wh   = sm + 9200;     // 12800 [v][f64]
    float* pbuf = sm + 22000;    // 800   [wave][200]
    float* e1   = sm + 22800;    // 200
    float* e2   = sm + 23000;    // 200
    float* P1s  = sm + 23200;    // 224
    float* Q1s  = sm + 23424;    // 224
    float* be1  = sm + 23648;    // 32
    float* W2s  = sm + 23680;    // 2048
    float* a2s  = sm + 25728;    // 128
    unsigned* adjb = (unsigned*)(sm + 25856); // 1400
    int bt = blockIdx.x, tid = threadIdx.x;
    int b = bt / 80, t = bt % 80;
    int lane = tid & 63, wv = tid >> 6;
    for (int i = tid; i < 224; i += 256){ P1s[i] = W[OFF_P1+i]; Q1s[i] = W[OFF_Q1+i]; }
    if (tid < 32) be1[tid] = W[OFF_BEFF1+tid];
    for (int i = tid; i < 2048; i += 256) W2s[i] = g2W[i];
    if (tid < 128) a2s[tid] = g2a[tid];
    const unsigned* gadj = (const unsigned*)(W + OFF_ADJB);
    for (int i = tid; i < 1400; i += 256) adjb[i] = gadj[i];
    for (int i = tid; i < 1400; i += 256){
        int dt = i/200, v = i%200, tp = t + dt - 3;
        float s = (tp >= 0 && tp < 80) ? W[OFF_S + (b*80+tp)*200 + v] : 0.f;
        sp7[i] = fmaxf(s, 0.f); sn7[i] = fmaxf(-s, 0.f);
    }
    __syncthreads();
    // h = conv1 output (raw)
    for (int i = tid; i < 6400; i += 256){
        int v = i/32, o = i%32;
        float acc = be1[o];
        #pragma unroll
        for (int dt = 0; dt < 7; dt++)
            acc += P1s[o*7+dt]*sp7[dt*200+v] + Q1s[o*7+dt]*sn7[dt*200+v];
        hh[i] = acc;
    }
    __syncthreads();
    // Wh = h @ g2W
    for (int i = tid; i < 12800; i += 256){
        int v = i/64, f = i%64;
        float acc = 0.f;
        #pragma unroll 8
        for (int c = 0; c < 32; c++) acc += hh[v*32+c]*W2s[c*64+f];
        wh[i] = acc;
    }
    __syncthreads();
    // e1,e2
    for (int v = wv; v < 200; v += 4){
        float whv = wh[v*64+lane];
        float z1 = whv * a2s[lane];
        float z2 = whv * a2s[64+lane];
        z1 = wsum(z1); z2 = wsum(z2);
        if (lane == 0){ e1[v] = z1; e2[v] = z2; }
    }
    __syncthreads();
    // masked softmax attention rows + att@Wh, store relu
    for (int v = wv; v < 200; v += 4){
        float ev = e1[v];
        float m = -3.4e38f;
        for (int j = lane; j < 200; j += 64){
            if ((adjb[v*7+(j>>5)]>>(j&31)) & 1u){
                float z = ev + e2[j];
                z = z > 0.f ? z : 0.2f*z;
                m = fmaxf(m, z);
            }
        }
        m = wmax(m);
        float den = 0.f;
        for (int j = lane; j < 200; j += 64){
            float p = 0.f;
            if ((adjb[v*7+(j>>5)]>>(j&31)) & 1u){
                float z = ev + e2[j];
                z = z > 0.f ? z : 0.2f*z;
                p = __expf(z - m);
            }
            pbuf[wv*200+j] = p;
            den += p;
        }
        den = wsum(den);
        float invd = 1.f/den;
        const float4* p4 = (const float4*)(pbuf + wv*200);
        float acc = 0.f;
        #pragma unroll 5
        for (int j4 = 0; j4 < 50; j4++){
            float4 pv = p4[j4];
            int j = j4*4;
            acc += pv.x*wh[(j  )*64+lane];
            acc += pv.y*wh[(j+1)*64+lane];
            acc += pv.z*wh[(j+2)*64+lane];
            acc += pv.w*wh[(j+3)*64+lane];
        }
        W[OFF_G2R + ((long)(b*80+t)*200 + v)*64 + lane] = fmaxf(acc*invd, 0.f);
    }
}

// ---------------- conv2 (7-tap, 64ch) + fb(64->16,leaky 0.1) fused ----------------
__global__ void __launch_bounds__(256) kconv2fb(const float* __restrict__ fbw, const float* __restrict__ fbb,
                                                float* __restrict__ W)
{
    extern __shared__ float sm[];
    float* tile = sm;           // 11008 = 2*86*64 (also reused as stage[160][64])
    float* fbws = sm + 11008;   // 16*65
    float* fbbs = sm + 12048;   // 16
    float* be2  = sm + 12064;   // 64
    int bid = blockIdx.x, tid = threadIdx.x;
    int b = bid/100, vp = bid%100, v0 = vp*2;
    int lane = tid & 63, wv = tid >> 6;
    for (int i = tid; i < 1024; i += 256) fbws[(i>>6)*65 + (i&63)] = fbw[i];
    if (tid < 16) fbbs[tid] = fbb[tid];
    if (tid < 64) be2[tid] = W[OFF_BEFF2+tid];
    for (int i = tid; i < 11008; i += 256){
        int vq = i/(86*64), tt = (i/64)%86, c = i%64, tp = tt-3;
        float val = 0.f;
        if (tp >= 0 && tp < 80) val = W[OFF_G2R + ((long)(b*80+tp)*200 + v0+vq)*64 + c];
        tile[i] = val;
    }
    __syncthreads();
    int vq = wv >> 1, t0 = (wv & 1)*40;
    float acc[40];
    #pragma unroll
    for (int k = 0; k < 40; k++) acc[k] = 0.f;
    for (int c = 0; c < 64; c++){
        float tvv[46];
        #pragma unroll
        for (int i = 0; i < 46; i++) tvv[i] = tile[(vq*86 + t0 + i)*64 + c];
        #pragma unroll
        for (int dt = 0; dt < 7; dt++){
            float wvv = W[OFF_W2L + (long)(c*7+dt)*64 + lane];
            #pragma unroll
            for (int k = 0; k < 40; k++) acc[k] += wvv * tvv[k+dt];
        }
    }
    __syncthreads();
    int row = wv*40;
    for (int k = 0; k < 40; k++) tile[(row+k)*64 + lane] = acc[k] + be2[lane];
    __syncthreads();
    for (int it = 0; it < 10; it++){
        int r = it*16 + (tid>>4), j = tid & 15;
        float a2 = fbbs[j];
        #pragma unroll 8
        for (int o = 0; o < 64; o++) a2 += fbws[j*65+o]*tile[r*64+o];
        a2 = a2 > 0.f ? a2 : 0.1f*a2;
        int vq2 = r/80, tt = r%80;
        W[OFF_Y + ((long)(b*80+tt)*200 + v0+vq2)*16 + j] = a2;
    }
}

// ---------------- sp linear 3200->64 ----------------
__global__ void __launch_bounds__(256) ksp(const float* __restrict__ sp_b, float* __restrict__ W)
{
    __shared__ float yb[3200];
    __shared__ float part[4][64];
    int bt = blockIdx.x, tid = threadIdx.x;
    int lane = tid & 63, wv = tid >> 6;
    for (int i = tid; i < 3200; i += 256) yb[i] = W[OFF_Y + (long)bt*3200 + i];
    __syncthreads();
    float acc = 0.f;
    int base = wv*800;
    for (int vj = 0; vj < 800; vj++)
        acc += W[OFF_SPWT + (long)(base+vj)*64 + lane] * yb[base+vj];
    part[wv][lane] = acc;
    __syncthreads();
    if (tid < 64){
        float s = part[0][tid]+part[1][tid]+part[2][tid]+part[3][tid] + sp_b[tid];
        W[OFF_XS0 + bt*64 + tid] = s;
    }
}

// ---------------- MHA + LN1 + FF + LN2 + mean(T) per batch ----------------
__global__ void __launch_bounds__(256) kattn(const float* __restrict__ inb, const float* __restrict__ ob,
    const float* __restrict__ l1g, const float* __restrict__ l1b,
    const float* __restrict__ l2g, const float* __restrict__ l2b,
    const float* __restrict__ f1b, const float* __restrict__ f2b,
    float* __restrict__ W)
{
    extern __shared__ float sm[];
    float* xb  = sm;          // 80*65
    float* qkv = sm + 5200;   // 80*193
    float* ao  = sm + 20640;  // 80*65
    float* pb  = sm + 25840;  // 4*80
    int b = blockIdx.x, tid = threadIdx.x, lane = tid & 63, wv = tid >> 6;
    for (int i = tid; i < 5120; i += 256){ int s = i>>6, c = i&63; xb[s*65+c] = W[OFF_XS0 + (b*80+s)*64 + c]; }
    __syncthreads();
    for (int s = wv; s < 80; s += 4){
        for (int ig = 0; ig < 3; ig++){
            int i = ig*64 + lane;
            float a = inb[i];
            #pragma unroll 8
            for (int c = 0; c < 64; c++) a += xb[s*65+c]*W[OFF_WINT + c*192 + i];
            qkv[s*193 + i] = a;
        }
    }
    __syncthreads();
    int h = wv;
    for (int i = 0; i < 80; i++){
        float qv[16];
        #pragma unroll
        for (int d = 0; d < 16; d++) qv[d] = qkv[i*193 + h*16 + d];
        float z[2];
        float m = -3.4e38f;
        #pragma unroll
        for (int u = 0; u < 2; u++){
            int jj = lane + u*64;
            z[u] = -3.4e38f;
            if (jj < 80){
                float a = 0.f;
                #pragma unroll
                for (int d = 0; d < 16; d++) a += qv[d]*qkv[jj*193 + 64 + h*16 + d];
                z[u] = a*0.25f;
                m = fmaxf(m, z[u]);
            }
        }
        m = wmax(m);
        float den = 0.f;
        #pragma unroll
        for (int u = 0; u < 2; u++){
            int jj = lane + u*64;
            if (jj < 80){
                float p = __expf(z[u]-m);
                pb[h*80+jj] = p;
                den += p;
            }
        }
        den = wsum(den);
        int d = lane & 15, jg = lane >> 4;
        float a = 0.f;
        for (int jo = 0; jo < 20; jo++){
            int jj = jg*20 + jo;
            a += pb[h*80+jj]*qkv[jj*193 + 128 + h*16 + d];
        }
        a += __shfl_xor(a, 16);
        a += __shfl_xor(a, 32);
        if (lane < 16) ao[i*65 + h*16 + lane] = a/den;
    }
    __syncthreads();
    for (int s = wv; s < 80; s += 4){
        float pr = ob[lane];
        #pragma unroll 8
        for (int e = 0; e < 64; e++) pr += ao[s*65+e]*W[OFF_OWT + e*64 + lane];
        float val = xb[s*65+lane] + pr;
        float mu = wsum(val)*(1.f/64.f);
        float dfv = val - mu;
        float var = wsum(dfv*dfv)*(1.f/64.f);
        xb[s*65+lane] = dfv*rsqrtf(var+1e-5f)*l1g[lane] + l1b[lane];
    }
    __syncthreads();
    for (int s = wv; s < 80; s += 4){
        for (int rg = 0; rg < 2; rg++){
            int r = rg*64+lane;
            float a = f1b[r];
            #pragma unroll 8
            for (int c = 0; c < 64; c++) a += xb[s*65+c]*W[OFF_F1T + c*128 + r];
            qkv[s*193 + r] = fmaxf(a, 0.f);
        }
    }
    __syncthreads();
    for (int s = wv; s < 80; s += 4){
        float a = f2b[lane];
        #pragma unroll 8
        for (int r = 0; r < 128; r++) a += qkv[s*193+r]*W[OFF_F2T + r*64 + lane];
        float val = xb[s*65+lane] + a;
        float mu = wsum(val)*(1.f/64.f);
        float dfv = val - mu;
        float var = wsum(dfv*dfv)*(1.f/64.f);
        xb[s*65+lane] = dfv*rsqrtf(var+1e-5f)*l2g[lane] + l2b[lane];
    }
    __syncthreads();
    if (tid < 64){
        float a = 0.f;
        for (int s = 0; s < 80; s++) a += xb[s*65+tid];
        W[OFF_FEATST + b*64 + tid] = a*(1.f/80.f);
    }
}

// ---------------- Gram: A = xc/sqrt(79), G = A A^T ----------------
__global__ void __launch_bounds__(256) kgram(const float* __restrict__ x, float* __restrict__ W)
{
    extern __shared__ float sm[]; // xb[16000]
    float* xb = sm;
    int b = blockIdx.x, tid = threadIdx.x;
    for (int i = tid; i < 16000; i += 256) xb[i] = x[b*16000 + i];
    __syncthreads();
    const float is79 = rsqrtf(79.f);
    if (tid < 200){
        int n = tid;
        float mu = 0.f;
        for (int t = 0; t < 80; t++) mu += xb[t*200+n];
        mu *= (1.f/80.f);
        for (int t = 0; t < 80; t++) xb[t*200+n] = (xb[t*200+n]-mu)*is79;
    }
    __syncthreads();
    for (int i = tid; i < 16000; i += 256) W[OFF_A + b*16000 + i] = xb[i];
    for (int idx = tid; idx < 6400; idx += 256){
        int i = idx/80, j = idx%80;
        float a = 0.f;
        for (int n = 0; n < 200; n++) a += xb[i*200+n]*xb[j*200+n];
        W[OFF_G + b*6400 + idx] = a;
    }
}

// ---------------- Jacobi eigendecomposition of G (80x80) + Rs = sqrt(f(L)) V^T A ----------------
__global__ void __launch_bounds__(256) kjacobi(float* __restrict__ W)
{
    extern __shared__ float sm[];
    float* Gs = sm;            // 80*81
    float* Vv = sm + 6480;     // 80*81
    float* Ab = sm + 12960;    // 16000
    float* cA = sm + 28960;    // 40
    float* sA = sm + 29000;    // 40
    int*   pA = (int*)(sm + 29040);
    int*   qA = (int*)(sm + 29080);
    float* dco = sm + 29120;   // 80
    float* red = sm + 29200;   // 8
    int*   flag = (int*)(sm + 29208);
    int b = blockIdx.x, tid = threadIdx.x, lane = tid & 63, wv = tid >> 6;
    for (int i = tid; i < 6400; i += 256){ int ii = i/80, jj = i%80; Gs[ii*81+jj] = W[OFF_G + b*6400 + i]; }
    for (int i = tid; i < 6480; i += 256) Vv[i] = 0.f;
    for (int i = tid; i < 16000; i += 256) Ab[i] = W[OFF_A + b*16000 + i];
    __syncthreads();
    if (tid < 80) Vv[tid*81+tid] = 1.f;
    __syncthreads();
    for (int sweep = 0; sweep < 12; sweep++){
        float off2 = 0.f, dia2 = 0.f;
        for (int i = tid; i < 6400; i += 256){
            int ii = i/80, jj = i%80;
            float v = Gs[ii*81+jj];
            if (ii < jj) off2 += v*v;
            else if (ii == jj) dia2 += v*v;
        }
        off2 = wsum(off2); dia2 = wsum(dia2);
        if (lane == 0){ red[wv*2] = off2; red[wv*2+1] = dia2; }
        __syncthreads();
        if (tid == 0){
            float o2 = red[0]+red[2]+red[4]+red[6];
            float d2 = red[1]+red[3]+red[5]+red[7];
            *flag = (o2 <= 1e-11f*d2) ? 1 : 0;
        }
        __syncthreads();
        if (*flag) break;
        for (int r = 0; r < 79; r++){
            if (tid < 40){
                int p, q;
                if (tid == 0){ p = 79; q = r; }
                else { p = (r + tid) % 79; q = (r - tid + 79) % 79; }
                float app = Gs[p*81+p], aqq = Gs[q*81+q], apq = Gs[p*81+q];
                float cc = 1.f, ss = 0.f;
                if (fabsf(apq) > 1e-30f){
                    float tau = (aqq-app)/(2.f*apq);
                    float tt = 1.f/(fabsf(tau)+sqrtf(1.f+tau*tau));
                    if (tau < 0.f) tt = -tt;
                    cc = rsqrtf(1.f+tt*tt);
                    ss = tt*cc;
                }
                cA[tid] = cc; sA[tid] = ss; pA[tid] = p; qA[tid] = q;
            }
            __syncthreads();
            for (int idx = tid; idx < 3200; idx += 256){
                int k = idx/80, j = idx%80;
                int p = pA[k], q = qA[k];
                float cc = cA[k], ss = sA[k];
                float gp = Gs[p*81+j], gq = Gs[q*81+j];
                Gs[p*81+j] = cc*gp - ss*gq;
                Gs[q*81+j] = ss*gp + cc*gq;
            }
            __syncthreads();
            for (int idx = tid; idx < 3200; idx += 256){
                int k = idx/80, i = idx%80;
                int p = pA[k], q = qA[k];
                float cc = cA[k], ss = sA[k];
                float gp = Gs[i*81+p], gq = Gs[i*81+q];
                Gs[i*81+p] = cc*gp - ss*gq;
                Gs[i*81+q] = ss*gp + cc*gq;
                float vp = Vv[i*81+p], vq = Vv[i*81+q];
                Vv[i*81+p] = cc*vp - ss*vq;
                Vv[i*81+q] = ss*vp + cc*vq;
            }
            __syncthreads();
        }
    }
    if (tid < 80){
        float lam = Gs[tid*81+tid];
        float dd = (lam > 1e-7f) ? log1pf(lam*1e4f)/lam : 1e4f;
        dco[tid] = sqrtf(dd);
    }
    __syncthreads();
    for (int idx = tid; idx < 16000; idx += 256){
        int i = idx/200, n = idx%200;
        float a = 0.f;
        for (int j = 0; j < 80; j++) a += Vv[j*81+i]*Ab[j*200+n];
        W[OFF_RS + b*16000 + idx] = dco[i]*a;
    }
}

// ---------------- tv = upper-tri(Rs^T Rs + logc*I) ----------------
__global__ void ktv(float* __restrict__ W)
{
    __shared__ float rsn[80];
    int bid = blockIdx.x, tid = threadIdx.x;
    int b = bid/200, n = bid%200;
    for (int i = tid; i < 80; i += 64) rsn[i] = W[OFF_RS + b*16000 + i*200 + n];
    __syncthreads();
    long tb = OFF_TV + (long)b*20100 + (long)n*200 - (long)n*(n-1)/2;
    for (int m = n + tid; m < 200; m += 64){
        float a = 0.f;
        for (int i = 0; i < 80; i++) a += rsn[i]*W[OFF_RS + b*16000 + i*200 + m];
        if (m == n) a += LOGC;
        W[tb + (m-n)] = a;
    }
}

// ---------------- tn1 linear 20100->256 (block per output r, all batches) ----------------
__global__ void __launch_bounds__(256) ktn1(const float* __restrict__ w, const float* __restrict__ bias,
                                            float* __restrict__ W)
{
    __shared__ float part[4][16];
    int r = blockIdx.x, tid = threadIdx.x, lane = tid & 63, wv = tid >> 6;
    float acc[16];
    #pragma unroll
    for (int i = 0; i < 16; i++) acc[i] = 0.f;
    for (int vj = tid; vj < 20100; vj += 256){
        float wvv = w[(long)r*20100 + vj];
        #pragma unroll
        for (int bb = 0; bb < 16; bb++) acc[bb] += wvv * W[OFF_TV + (long)bb*20100 + vj];
    }
    #pragma unroll
    for (int bb = 0; bb < 16; bb++) acc[bb] = wsum(acc[bb]);
    if (lane == 0){
        #pragma unroll
        for (int bb = 0; bb < 16; bb++) part[wv][bb] = acc[bb];
    }
    __syncthreads();
    if (tid < 16){
        float s = part[0][tid]+part[1][tid]+part[2][tid]+part[3][tid] + bias[r];
        W[OFF_TN1O + tid*256 + r] = s;
    }
}

// ---------------- head: tn2 + concat + cls/site ----------------
__global__ void khead(const float* __restrict__ tn2w, const float* __restrict__ tn2b,
                      const float* __restrict__ cl1w, const float* __restrict__ cl1b,
                      const float* __restrict__ cl2w, const float* __restrict__ cl2b,
                      const float* __restrict__ sc1w, const float* __restrict__ sc1b,
                      const float* __restrict__ sc2w, const float* __restrict__ sc2b,
                      const float* __restrict__ W, float* __restrict__ out)
{
    __shared__ float g[256], feats[128], h1[64], h2[32];
    int tid = threadIdx.x;
    for (int b = 0; b < 16; b++){
        float v = W[OFF_TN1O + b*256 + tid] * BN_SC;
        g[tid] = v > 0.f ? v : 0.1f*v;
        __syncthreads();
        if (tid < 64){
            float a = tn2b[tid];
            for (int r = 0; r < 256; r++) a += tn2w[tid*256+r]*g[r];
            feats[64+tid] = fmaxf(a, 0.f);
            feats[tid] = W[OFF_FEATST + b*64 + tid];
        }
        __syncthreads();
        if (tid < 64){
            float a = cl1b[tid];
            for (int k = 0; k < 128; k++) a += cl1w[tid*128+k]*feats[k];
            h1[tid] = fmaxf(a, 0.f);
        } else if (tid < 96){
            int i = tid-64;
            float a = sc1b[i];
            for (int k = 0; k < 128; k++) a += sc1w[i*128+k]*feats[k];
            h2[i] = fmaxf(a, 0.f);
        }
        __syncthreads();
        if (tid < 2){
            float a = cl2b[tid];
            for (int i = 0; i < 64; i++) a += cl2w[tid*64+i]*h1[i];
            out[b*2+tid] = a;
        } else if (tid >= 32 && tid < 49){
            int o = tid-32;
            float a = sc2b[o];
            for (int i = 0; i < 32; i++) a += sc2w[o*32+i]*h2[i];
            out[32 + b*17 + o] = a;
        }
        __syncthreads();
    }
}

extern "C" void kernel_launch(void* const* d_in, const int* in_sizes, int n_in,
                              void* d_out, int out_size, void* d_ws, size_t ws_size,
                              hipStream_t stream)
{
    const float* x     = (const float*)d_in[0];
    const float* adj   = (const float*)d_in[1];
    const float* g1W   = (const float*)d_in[2];
    const float* g1a   = (const float*)d_in[3];
    const float* b1c3w = (const float*)d_in[4];
    const float* b1c3b = (const float*)d_in[5];
    const float* b1c5w = (const float*)d_in[6];
    const float* b1c5b = (const float*)d_in[7];
    const float* b1c7w = (const float*)d_in[8];
    const float* b1c7b = (const float*)d_in[9];
    const float* b1fw  = (const float*)d_in[10];
    const float* b1fb  = (const float*)d_in[11];
    const float* g2W   = (const float*)d_in[12];
    const float* g2a   = (const float*)d_in[13];
    const float* b2c3w = (const float*)d_in[14];
    const float* b2c3b = (const float*)d_in[15];
    const float* b2c5w = (const float*)d_in[16];
    const float* b2c5b = (const float*)d_in[17];
    const float* b2c7w = (const float*)d_in[18];
    const float* b2c7b = (const float*)d_in[19];
    const float* b2fw  = (const float*)d_in[20];
    const float* b2fb  = (const float*)d_in[21];
    const float* fbw   = (const float*)d_in[22];
    const float* fbb   = (const float*)d_in[23];
    const float* spw   = (const float*)d_in[24];
    const float* spb   = (const float*)d_in[25];
    const float* ainw  = (const float*)d_in[26];
    const float* ainb  = (const float*)d_in[27];
    const float* aow   = (const float*)d_in[28];
    const float* aob   = (const float*)d_in[29];
    const float* ln1g  = (const float*)d_in[30];
    const float* ln1b  = (const float*)d_in[31];
    const float* ln2g  = (const float*)d_in[32];
    const float* ln2b  = (const float*)d_in[33];
    const float* ff1w  = (const float*)d_in[34];
    const float* ff1b  = (const float*)d_in[35];
    const float* ff2w  = (const float*)d_in[36];
    const float* ff2b  = (const float*)d_in[37];
    const float* tn1w  = (const float*)d_in[38];
    const float* tn1b  = (const float*)d_in[39];
    const float* tn2w  = (const float*)d_in[40];
    const float* tn2b  = (const float*)d_in[41];
    const float* cl1w  = (const float*)d_in[42];
    const float* cl1b  = (const float*)d_in[43];
    const float* cl2w  = (const float*)d_in[44];
    const float* cl2b  = (const float*)d_in[45];
    const float* sc1w  = (const float*)d_in[46];
    const float* sc1b  = (const float*)d_in[47];
    const float* sc2w  = (const float*)d_in[48];
    const float* sc2b  = (const float*)d_in[49];
    float* W = (float*)d_ws;
    float* out = (float*)d_out;

    kprep1<<<128, 256, 0, stream>>>(spw, b2fw, b2c3w, b2c5w, b2c7w, b2c3b, b2c5b, b2c7b, b2fb, W);
    kprep2<<<1, 256, 0, stream>>>(g1W, g1a, b1c3w, b1c5w, b1c7w, b1c3b, b1c5b, b1c7b, b1fw, b1fb,
                                  adj, ainw, aow, ff1w, ff2w, W);
    kgat1<<<1280, 256, 0, stream>>>(x, W);
    kgat2<<<1280, 256, 109056, stream>>>(g2W, g2a, W);
    kconv2fb<<<1600, 256, 48512, stream>>>(fbw, fbb, W);
    ksp<<<1280, 256, 0, stream>>>(spb, W);
    kattn<<<16, 256, 104640, stream>>>(ainb, aob, ln1g, ln1b, ln2g, ln2b, ff1b, ff2b, W);
    kgram<<<16, 256, 64000, stream>>>(x, W);
    kjacobi<<<16, 256, 116864, stream>>>(W);
    ktv<<<3200, 64, 0, stream>>>(W);
    ktn1<<<256, 256, 0, stream>>>(tn1w, tn1b, W);
    khead<<<1, 256, 0, stream>>>(tn2w, tn2b, cl1w, cl1b, cl2w, cl2b, sc1w, sc1b, sc2w, sc2b, W, out);
}

// Round 2
// 4167.145 us; speedup vs baseline: 1.2102x; 1.2102x over previous
//
#include <hip/hip_runtime.h>
#include <math.h>

#define BN_SC 0.9999950000374997f
#define BN2   0.9999900000999990f
#define LOGC  (-9.210340371976184f)

// ---- ws float offsets ----
#define OFF_S      0L         // 1280*200
#define OFF_ADJB   256000L    // 1400 uints
#define OFF_P1     257408L    // 224
#define OFF_Q1     257664L    // 224
#define OFF_BEFF1  257920L    // 32
#define OFF_BEFF2  257952L    // 64
#define OFF_C12    258016L    // 2
#define OFF_W2L    258304L    // 28672  [c][dt][o]
#define OFF_SPWT   286976L    // 204800 [vj][d]
#define OFF_WINT   491776L    // 12288  [c][i]
#define OFF_OWT    504064L    // 4096   [e][d]
#define OFF_F1T    508160L    // 8192   [c][r]
#define OFF_F2T    516352L    // 8192   [r][c]
#define OFF_FEATST 524544L    // 1024
#define OFF_XS0    525568L    // 81920
#define OFF_TN1O   607488L    // 4096
#define OFF_A      611584L    // 256000
#define OFF_G      867584L    // 102400
#define OFF_RS     969984L    // 256000
#define OFF_TV     1225984L   // 321600
#define OFF_Y      1547584L   // 4096000
#define OFF_G2R    5643584L   // 16384000
// total 22,027,584 floats = 88.1 MB

__device__ inline float wsum(float v){ for(int o=32;o>0;o>>=1) v += __shfl_xor(v,o); return v; }
__device__ inline float wmax(float v){ for(int o=32;o>0;o>>=1) v = fmaxf(v,__shfl_xor(v,o)); return v; }

// round-robin Jacobi pair schedule: element 79 fixed, others rotate
__device__ inline void jpair(int r, int k, int& p, int& q){
    if (k == 0){ p = 79; q = r; }
    else {
        int s0 = r + k; p = s0 - (s0 >= 79 ? 79 : 0);
        int s1 = r - k; q = s1 + (s1 < 0 ? 79 : 0);
    }
}

// ---------------- prep 1: spwT transpose + Weff2 + beff2 ----------------
__global__ void kprep1(const float* __restrict__ sp_w,
                       const float* __restrict__ fw2,
                       const float* __restrict__ w3, const float* __restrict__ w5, const float* __restrict__ w7,
                       const float* __restrict__ b3, const float* __restrict__ b5, const float* __restrict__ b7,
                       const float* __restrict__ fb2,
                       float* __restrict__ W)
{
    int bid = blockIdx.x, tid = threadIdx.x;
    if (bid < 64) {
        int d = bid;
        for (int vj = tid; vj < 3200; vj += 256)
            W[OFF_SPWT + (long)vj*64 + d] = sp_w[d*3200 + vj];
    } else {
        int o = bid - 64;
        for (int idx = tid; idx < 448; idx += 256) {
            int c = idx / 7, dt = idx % 7;
            float acc = 0.f;
            for (int cp = 0; cp < 64; cp++) {
                float f3 = fw2[o*192 + cp], f5 = fw2[o*192 + 64 + cp], f7 = fw2[o*192 + 128 + cp];
                if (dt >= 2 && dt <= 4) acc += f3 * w3[(cp*64 + c)*3 + (dt-2)];
                if (dt >= 1 && dt <= 5) acc += f5 * w5[(cp*64 + c)*5 + (dt-1)];
                acc += f7 * w7[(cp*64 + c)*7 + dt];
            }
            W[OFF_W2L + (long)(c*7+dt)*64 + o] = acc * BN2;
        }
        if (tid == 0) {
            float acc = fb2[o];
            for (int cp = 0; cp < 64; cp++)
                acc += (fw2[o*192+cp]*b3[cp] + fw2[o*192+64+cp]*b5[cp] + fw2[o*192+128+cp]*b7[cp]) * BN_SC;
            W[OFF_BEFF2 + o] = acc;
        }
    }
}

// ---------------- prep 2: c1/c2, P1/Q1, beff1, adj bitmask, transposes ----------------
__global__ void kprep2(const float* __restrict__ g1W, const float* __restrict__ g1a,
                       const float* __restrict__ w3, const float* __restrict__ w5, const float* __restrict__ w7,
                       const float* __restrict__ b3, const float* __restrict__ b5, const float* __restrict__ b7,
                       const float* __restrict__ fw1, const float* __restrict__ fb1,
                       const float* __restrict__ adj,
                       const float* __restrict__ inw, const float* __restrict__ ow,
                       const float* __restrict__ f1, const float* __restrict__ f2,
                       float* __restrict__ W)
{
    __shared__ float weff[7168]; // [o][c][dt] 32*32*7
    int tid = threadIdx.x;
    if (tid == 0) {
        float c1 = 0.f, c2 = 0.f;
        for (int f = 0; f < 32; f++){ c1 += g1W[f]*g1a[f]; c2 += g1W[f]*g1a[32+f]; }
        W[OFF_C12] = c1; W[OFF_C12+1] = c2;
    }
    for (int idx = tid; idx < 7168; idx += 256) {
        int o = idx/224, rem = idx%224, c = rem/7, dt = rem%7;
        float acc = 0.f;
        for (int cp = 0; cp < 32; cp++) {
            float f3 = fw1[o*96+cp], f5 = fw1[o*96+32+cp], f7 = fw1[o*96+64+cp];
            if (dt >= 2 && dt <= 4) acc += f3*w3[(cp*32+c)*3+(dt-2)];
            if (dt >= 1 && dt <= 5) acc += f5*w5[(cp*32+c)*5+(dt-1)];
            acc += f7*w7[(cp*32+c)*7+dt];
        }
        weff[idx] = acc * BN2;
    }
    __syncthreads();
    for (int idx = tid; idx < 224; idx += 256) {
        int o = idx/7, dt = idx%7;
        float p = 0.f, q = 0.f;
        for (int c = 0; c < 32; c++){
            float wv = weff[o*224 + c*7 + dt];
            float w0 = g1W[c];
            p += wv * fmaxf(w0, 0.f);
            q += wv * fmaxf(-w0, 0.f);
        }
        W[OFF_P1 + idx] = p; W[OFF_Q1 + idx] = q;
    }
    if (tid < 32) {
        int o = tid;
        float acc = fb1[o];
        for (int cp = 0; cp < 32; cp++)
            acc += (fw1[o*96+cp]*b3[cp] + fw1[o*96+32+cp]*b5[cp] + fw1[o*96+64+cp]*b7[cp]) * BN_SC;
        W[OFF_BEFF1+o] = acc;
    }
    unsigned* adjb = (unsigned*)(W + OFF_ADJB);
    for (int idx = tid; idx < 1400; idx += 256) {
        int v = idx/7, qw = idx%7;
        unsigned bits = 0;
        for (int k = 0; k < 32; k++){ int j = qw*32+k; if (j < 200 && adj[v*200+j] > 0.f) bits |= (1u<<k); }
        adjb[idx] = bits;
    }
    for (int idx = tid; idx < 12288; idx += 256){ int i = idx%192; int c = idx/192; W[OFF_WINT+idx] = inw[i*64+c]; }
    for (int idx = tid; idx < 4096;  idx += 256){ int d = idx%64;  int e = idx/64;  W[OFF_OWT+idx]  = ow[d*64+e]; }
    for (int idx = tid; idx < 8192;  idx += 256){ int r = idx%128; int c = idx/128; W[OFF_F1T+idx]  = f1[r*64+c]; }
    for (int idx = tid; idx < 8192;  idx += 256){ int c = idx%64;  int r = idx/64;  W[OFF_F2T+idx]  = f2[c*128+r]; }
}

// ---------------- GAT1 (scalar-feature collapse): s[bt][v] ----------------
__global__ void __launch_bounds__(256) kgat1(const float* __restrict__ x, float* __restrict__ W)
{
    __shared__ float xrow[200];
    __shared__ unsigned adjb[1400];
    int bt = blockIdx.x, tid = threadIdx.x;
    int lane = tid & 63, wv = tid >> 6;
    const unsigned* gadj = (const unsigned*)(W + OFF_ADJB);
    for (int i = tid; i < 200; i += 256) xrow[i] = x[bt*200+i];
    for (int i = tid; i < 1400; i += 256) adjb[i] = gadj[i];
    __syncthreads();
    float c1 = W[OFF_C12], c2 = W[OFF_C12+1];
    for (int v = wv; v < 200; v += 4) {
        float xv = xrow[v];
        float m = -3.4e38f;
        for (int j = lane; j < 200; j += 64) {
            if ((adjb[v*7 + (j>>5)] >> (j&31)) & 1u) {
                float z = c1*xv + c2*xrow[j];
                z = z > 0.f ? z : 0.2f*z;
                m = fmaxf(m, z);
            }
        }
        m = wmax(m);
        float den = 0.f, num = 0.f;
        for (int j = lane; j < 200; j += 64) {
            if ((adjb[v*7 + (j>>5)] >> (j&31)) & 1u) {
                float z = c1*xv + c2*xrow[j];
                z = z > 0.f ? z : 0.2f*z;
                float p = __expf(z - m);
                den += p; num += p * xrow[j];
            }
        }
        den = wsum(den); num = wsum(num);
        if (lane == 0) W[OFF_S + bt*200 + v] = num / den;
    }
}

// ---------------- GAT2 with conv1 fused in (per (b,t) block) ----------------
__global__ void __launch_bounds__(256) kgat2(const float* __restrict__ g2W, const float* __restrict__ g2a,
                                             float* __restrict__ W)
{
    extern __shared__ float sm[];
    float* sp7  = sm;            // 1400
    float* sn7  = sm + 1400;     // 1400
    float* hh   = sm + 2800;     // 6400  [v][c32]
    float* wh   = sm + 9200;     // 12800 [v][f64]
    float* pbuf = sm + 22000;    // 800   [wave][200]
    float* e1   = sm + 22800;    // 200
    float* e2   = sm + 23000;    // 200
    float* P1s  = sm + 23200;    // 224
    float* Q1s  = sm + 23424;    // 224
    float* be1  = sm + 23648;    // 32
    float* W2s  = sm + 23680;    // 2048
    float* a2s  = sm + 25728;    // 128
    unsigned* adjb = (unsigned*)(sm + 25856); // 1400
    int bt = blockIdx.x, tid = threadIdx.x;
    int b = bt / 80, t = bt % 80;
    int lane = tid & 63, wv = tid >> 6;
    for (int i = tid; i < 224; i += 256){ P1s[i] = W[OFF_P1+i]; Q1s[i] = W[OFF_Q1+i]; }
    if (tid < 32) be1[tid] = W[OFF_BEFF1+tid];
    for (int i = tid; i < 2048; i += 256) W2s[i] = g2W[i];
    if (tid < 128) a2s[tid] = g2a[tid];
    const unsigned* gadj = (const unsigned*)(W + OFF_ADJB);
    for (int i = tid; i < 1400; i += 256) adjb[i] = gadj[i];
    for (int i = tid; i < 1400; i += 256){
        int dt = i/200, v = i%200, tp = t + dt - 3;
        float s = (tp >= 0 && tp < 80) ? W[OFF_S + (b*80+tp)*200 + v] : 0.f;
        sp7[i] = fmaxf(s, 0.f); sn7[i] = fmaxf(-s, 0.f);
    }
    __syncthreads();
    // h = conv1 output (raw)
    for (int i = tid; i < 6400; i += 256){
        int v = i/32, o = i%32;
        float acc = be1[o];
        #pragma unroll
        for (int dt = 0; dt < 7; dt++)
            acc += P1s[o*7+dt]*sp7[dt*200+v] + Q1s[o*7+dt]*sn7[dt*200+v];
        hh[i] = acc;
    }
    __syncthreads();
    // Wh = h @ g2W
    for (int i = tid; i < 12800; i += 256){
        int v = i/64, f = i%64;
        float acc = 0.f;
        #pragma unroll 8
        for (int c = 0; c < 32; c++) acc += hh[v*32+c]*W2s[c*64+f];
        wh[i] = acc;
    }
    __syncthreads();
    // e1,e2
    for (int v = wv; v < 200; v += 4){
        float whv = wh[v*64+lane];
        float z1 = whv * a2s[lane];
        float z2 = whv * a2s[64+lane];
        z1 = wsum(z1); z2 = wsum(z2);
        if (lane == 0){ e1[v] = z1; e2[v] = z2; }
    }
    __syncthreads();
    // masked softmax attention rows + att@Wh, store relu
    for (int v = wv; v < 200; v += 4){
        float ev = e1[v];
        float m = -3.4e38f;
        for (int j = lane; j < 200; j += 64){
            if ((adjb[v*7+(j>>5)]>>(j&31)) & 1u){
                float z = ev + e2[j];
                z = z > 0.f ? z : 0.2f*z;
                m = fmaxf(m, z);
            }
        }
        m = wmax(m);
        float den = 0.f;
        for (int j = lane; j < 200; j += 64){
            float p = 0.f;
            if ((adjb[v*7+(j>>5)]>>(j&31)) & 1u){
                float z = ev + e2[j];
                z = z > 0.f ? z : 0.2f*z;
                p = __expf(z - m);
            }
            pbuf[wv*200+j] = p;
            den += p;
        }
        den = wsum(den);
        float invd = 1.f/den;
        const float4* p4 = (const float4*)(pbuf + wv*200);
        float acc = 0.f;
        #pragma unroll 5
        for (int j4 = 0; j4 < 50; j4++){
            float4 pv = p4[j4];
            int j = j4*4;
            acc += pv.x*wh[(j  )*64+lane];
            acc += pv.y*wh[(j+1)*64+lane];
            acc += pv.z*wh[(j+2)*64+lane];
            acc += pv.w*wh[(j+3)*64+lane];
        }
        W[OFF_G2R + ((long)(b*80+t)*200 + v)*64 + lane] = fmaxf(acc*invd, 0.f);
    }
}

// ---------------- conv2 (7-tap, 64ch) + fb(64->16,leaky 0.1) fused ----------------
__global__ void __launch_bounds__(256) kconv2fb(const float* __restrict__ fbw, const float* __restrict__ fbb,
                                                float* __restrict__ W)
{
    extern __shared__ float sm[];
    float* tile = sm;           // 11008 = 2*86*64 (also reused as stage[160][64])
    float* fbws = sm + 11008;   // 16*65
    float* fbbs = sm + 12048;   // 16
    float* be2  = sm + 12064;   // 64
    int bid = blockIdx.x, tid = threadIdx.x;
    int b = bid/100, vp = bid%100, v0 = vp*2;
    int lane = tid & 63, wv = tid >> 6;
    for (int i = tid; i < 1024; i += 256) fbws[(i>>6)*65 + (i&63)] = fbw[i];
    if (tid < 16) fbbs[tid] = fbb[tid];
    if (tid < 64) be2[tid] = W[OFF_BEFF2+tid];
    for (int i = tid; i < 11008; i += 256){
        int vq = i/(86*64), tt = (i/64)%86, c = i%64, tp = tt-3;
        float val = 0.f;
        if (tp >= 0 && tp < 80) val = W[OFF_G2R + ((long)(b*80+tp)*200 + v0+vq)*64 + c];
        tile[i] = val;
    }
    __syncthreads();
    int vq = wv >> 1, t0 = (wv & 1)*40;
    float acc[40];
    #pragma unroll
    for (int k = 0; k < 40; k++) acc[k] = 0.f;
    for (int c = 0; c < 64; c++){
        float tvv[46];
        #pragma unroll
        for (int i = 0; i < 46; i++) tvv[i] = tile[(vq*86 + t0 + i)*64 + c];
        #pragma unroll
        for (int dt = 0; dt < 7; dt++){
            float wvv = W[OFF_W2L + (long)(c*7+dt)*64 + lane];
            #pragma unroll
            for (int k = 0; k < 40; k++) acc[k] += wvv * tvv[k+dt];
        }
    }
    __syncthreads();
    int row = wv*40;
    for (int k = 0; k < 40; k++) tile[(row+k)*64 + lane] = acc[k] + be2[lane];
    __syncthreads();
    for (int it = 0; it < 10; it++){
        int r = it*16 + (tid>>4), j = tid & 15;
        float a2 = fbbs[j];
        #pragma unroll 8
        for (int o = 0; o < 64; o++) a2 += fbws[j*65+o]*tile[r*64+o];
        a2 = a2 > 0.f ? a2 : 0.1f*a2;
        int vq2 = r/80, tt = r%80;
        W[OFF_Y + ((long)(b*80+tt)*200 + v0+vq2)*16 + j] = a2;
    }
}

// ---------------- sp linear 3200->64 ----------------
__global__ void __launch_bounds__(256) ksp(const float* __restrict__ sp_b, float* __restrict__ W)
{
    __shared__ float yb[3200];
    __shared__ float part[4][64];
    int bt = blockIdx.x, tid = threadIdx.x;
    int lane = tid & 63, wv = tid >> 6;
    for (int i = tid; i < 3200; i += 256) yb[i] = W[OFF_Y + (long)bt*3200 + i];
    __syncthreads();
    float acc = 0.f;
    int base = wv*800;
    for (int vj = 0; vj < 800; vj++)
        acc += W[OFF_SPWT + (long)(base+vj)*64 + lane] * yb[base+vj];
    part[wv][lane] = acc;
    __syncthreads();
    if (tid < 64){
        float s = part[0][tid]+part[1][tid]+part[2][tid]+part[3][tid] + sp_b[tid];
        W[OFF_XS0 + bt*64 + tid] = s;
    }
}

// ---------------- MHA + LN1 + FF + LN2 + mean(T) per batch ----------------
__global__ void __launch_bounds__(256) kattn(const float* __restrict__ inb, const float* __restrict__ ob,
    const float* __restrict__ l1g, const float* __restrict__ l1b,
    const float* __restrict__ l2g, const float* __restrict__ l2b,
    const float* __restrict__ f1b, const float* __restrict__ f2b,
    float* __restrict__ W)
{
    extern __shared__ float sm[];
    float* xb  = sm;          // 80*65
    float* qkv = sm + 5200;   // 80*193
    float* ao  = sm + 20640;  // 80*65
    float* pb  = sm + 25840;  // 4*80
    int b = blockIdx.x, tid = threadIdx.x, lane = tid & 63, wv = tid >> 6;
    for (int i = tid; i < 5120; i += 256){ int s = i>>6, c = i&63; xb[s*65+c] = W[OFF_XS0 + (b*80+s)*64 + c]; }
    __syncthreads();
    for (int s = wv; s < 80; s += 4){
        for (int ig = 0; ig < 3; ig++){
            int i = ig*64 + lane;
            float a = inb[i];
            #pragma unroll 8
            for (int c = 0; c < 64; c++) a += xb[s*65+c]*W[OFF_WINT + c*192 + i];
            qkv[s*193 + i] = a;
        }
    }
    __syncthreads();
    int h = wv;
    for (int i = 0; i < 80; i++){
        float qv[16];
        #pragma unroll
        for (int d = 0; d < 16; d++) qv[d] = qkv[i*193 + h*16 + d];
        float z[2];
        float m = -3.4e38f;
        #pragma unroll
        for (int u = 0; u < 2; u++){
            int jj = lane + u*64;
            z[u] = -3.4e38f;
            if (jj < 80){
                float a = 0.f;
                #pragma unroll
                for (int d = 0; d < 16; d++) a += qv[d]*qkv[jj*193 + 64 + h*16 + d];
                z[u] = a*0.25f;
                m = fmaxf(m, z[u]);
            }
        }
        m = wmax(m);
        float den = 0.f;
        #pragma unroll
        for (int u = 0; u < 2; u++){
            int jj = lane + u*64;
            if (jj < 80){
                float p = __expf(z[u]-m);
                pb[h*80+jj] = p;
                den += p;
            }
        }
        den = wsum(den);
        int d = lane & 15, jg = lane >> 4;
        float a = 0.f;
        for (int jo = 0; jo < 20; jo++){
            int jj = jg*20 + jo;
            a += pb[h*80+jj]*qkv[jj*193 + 128 + h*16 + d];
        }
        a += __shfl_xor(a, 16);
        a += __shfl_xor(a, 32);
        if (lane < 16) ao[i*65 + h*16 + lane] = a/den;
    }
    __syncthreads();
    for (int s = wv; s < 80; s += 4){
        float pr = ob[lane];
        #pragma unroll 8
        for (int e = 0; e < 64; e++) pr += ao[s*65+e]*W[OFF_OWT + e*64 + lane];
        float val = xb[s*65+lane] + pr;
        float mu = wsum(val)*(1.f/64.f);
        float dfv = val - mu;
        float var = wsum(dfv*dfv)*(1.f/64.f);
        xb[s*65+lane] = dfv*rsqrtf(var+1e-5f)*l1g[lane] + l1b[lane];
    }
    __syncthreads();
    for (int s = wv; s < 80; s += 4){
        for (int rg = 0; rg < 2; rg++){
            int r = rg*64+lane;
            float a = f1b[r];
            #pragma unroll 8
            for (int c = 0; c < 64; c++) a += xb[s*65+c]*W[OFF_F1T + c*128 + r];
            qkv[s*193 + r] = fmaxf(a, 0.f);
        }
    }
    __syncthreads();
    for (int s = wv; s < 80; s += 4){
        float a = f2b[lane];
        #pragma unroll 8
        for (int r = 0; r < 128; r++) a += qkv[s*193+r]*W[OFF_F2T + r*64 + lane];
        float val = xb[s*65+lane] + a;
        float mu = wsum(val)*(1.f/64.f);
        float dfv = val - mu;
        float var = wsum(dfv*dfv)*(1.f/64.f);
        xb[s*65+lane] = dfv*rsqrtf(var+1e-5f)*l2g[lane] + l2b[lane];
    }
    __syncthreads();
    if (tid < 64){
        float a = 0.f;
        for (int s = 0; s < 80; s++) a += xb[s*65+tid];
        W[OFF_FEATST + b*64 + tid] = a*(1.f/80.f);
    }
}

// ---------------- Gram: A = xc/sqrt(79), G = A A^T ----------------
__global__ void __launch_bounds__(256) kgram(const float* __restrict__ x, float* __restrict__ W)
{
    extern __shared__ float sm[]; // xb[16000]
    float* xb = sm;
    int b = blockIdx.x, tid = threadIdx.x;
    for (int i = tid; i < 16000; i += 256) xb[i] = x[b*16000 + i];
    __syncthreads();
    const float is79 = rsqrtf(79.f);
    if (tid < 200){
        int n = tid;
        float mu = 0.f;
        for (int t = 0; t < 80; t++) mu += xb[t*200+n];
        mu *= (1.f/80.f);
        for (int t = 0; t < 80; t++) xb[t*200+n] = (xb[t*200+n]-mu)*is79;
    }
    __syncthreads();
    for (int i = tid; i < 16000; i += 256) W[OFF_A + b*16000 + i] = xb[i];
    for (int idx = tid; idx < 6400; idx += 256){
        int i = idx/80, j = idx%80;
        float a = 0.f;
        for (int n = 0; n < 200; n++) a += xb[i*200+n]*xb[j*200+n];
        W[OFF_G + b*6400 + idx] = a;
    }
}

// ---------------- Jacobi eigendecomposition of G (80x80), in-place 2x2-block rounds ----------------
// LDS: Gs[80*81] | VT[80*82] (V transposed, even stride for float2) | Ab[16000] | cs[80] | red[8] | flag
__global__ void __launch_bounds__(256) kjacobi(float* __restrict__ W)
{
    extern __shared__ float sm[];
    float* Gs = sm;            // 6480
    float* VT = sm + 6480;     // 6560
    float* Ab = sm + 13040;    // 16000
    float* cs = sm + 29040;    // 80 (c,s interleaved)
    float* red = sm + 29120;   // 8
    int* flag = (int*)(sm + 29128);
    int b = blockIdx.x, tid = threadIdx.x, lane = tid & 63, wv = tid >> 6;
    for (int i = tid; i < 6400; i += 256){ int ii = i/80, jj = i%80; Gs[ii*81+jj] = W[OFF_G + b*6400 + i]; }
    for (int i = tid; i < 6560; i += 256) VT[i] = 0.f;
    for (int i = tid; i < 16000; i += 256) Ab[i] = W[OFF_A + b*16000 + i];
    __syncthreads();
    if (tid < 80) VT[tid*82+tid] = 1.f;
    __syncthreads();
    for (int sweep = 0; sweep < 12; sweep++){
        if (sweep >= 6){
            float off2 = 0.f, dia2 = 0.f;
            for (int i = tid; i < 6400; i += 256){
                int ii = i/80, jj = i%80;
                float v = Gs[ii*81+jj];
                if (ii < jj) off2 += v*v;
                else if (ii == jj) dia2 += v*v;
            }
            off2 = wsum(off2); dia2 = wsum(dia2);
            if (lane == 0){ red[wv*2] = off2; red[wv*2+1] = dia2; }
            __syncthreads();
            if (tid == 0){
                float o2 = red[0]+red[2]+red[4]+red[6];
                float d2 = red[1]+red[3]+red[5]+red[7];
                *flag = (o2 <= 1e-10f*d2) ? 1 : 0;
            }
            __syncthreads();
            if (*flag) break;
        }
        for (int r = 0; r < 79; r++){
            if (tid < 40){
                int p, q; jpair(r, tid, p, q);
                float app = Gs[p*81+p], aqq = Gs[q*81+q], apq = Gs[p*81+q];
                float cc = 1.f, ss = 0.f;
                if (fabsf(apq) > 1e-12f){
                    float tau = (aqq-app)/(2.f*apq);
                    float t = 1.f/(fabsf(tau)+sqrtf(1.f+tau*tau));
                    if (tau < 0.f) t = -t;
                    cc = rsqrtf(1.f+t*t);
                    ss = t*cc;
                }
                cs[2*tid] = cc; cs[2*tid+1] = ss;
            }
            __syncthreads();
            // G: 40x40 disjoint 2x2 blocks, in-place similarity update
            for (int idx = tid; idx < 1600; idx += 256){
                int k = idx/40, l = idx%40;
                int pk, qk, pl, ql;
                jpair(r, k, pk, qk); jpair(r, l, pl, ql);
                float2 csk = *(float2*)&cs[2*k];
                float2 csl = *(float2*)&cs[2*l];
                float a00 = Gs[pk*81+pl], a01 = Gs[pk*81+ql];
                float a10 = Gs[qk*81+pl], a11 = Gs[qk*81+ql];
                float b00 = csk.x*a00 - csk.y*a10;
                float b01 = csk.x*a01 - csk.y*a11;
                float b10 = csk.y*a00 + csk.x*a10;
                float b11 = csk.y*a01 + csk.x*a11;
                Gs[pk*81+pl] = csl.x*b00 - csl.y*b01;
                Gs[pk*81+ql] = csl.y*b00 + csl.x*b01;
                Gs[qk*81+pl] = csl.x*b10 - csl.y*b11;
                Gs[qk*81+ql] = csl.y*b10 + csl.x*b11;
            }
            // V: column rotation on VT rows, float2 over 2 consecutive i
            for (int idx = tid; idx < 1600; idx += 256){
                int l = idx/40, ip = idx%40;
                int i2 = ip*2;
                int pl, ql; jpair(r, l, pl, ql);
                float2 csl = *(float2*)&cs[2*l];
                float2 vp = *(float2*)&VT[pl*82+i2];
                float2 vq = *(float2*)&VT[ql*82+i2];
                float2 np, nq;
                np.x = csl.x*vp.x - csl.y*vq.x; np.y = csl.x*vp.y - csl.y*vq.y;
                nq.x = csl.y*vp.x + csl.x*vq.x; nq.y = csl.y*vp.y + csl.x*vq.y;
                *(float2*)&VT[pl*82+i2] = np;
                *(float2*)&VT[ql*82+i2] = nq;
            }
            __syncthreads();
        }
    }
    if (tid < 80){
        float lam = Gs[tid*81+tid];
        float dd = (lam > 1e-7f) ? log1pf(lam*1e4f)/lam : 1e4f;
        cs[tid] = sqrtf(dd);   // reuse cs as dco
    }
    __syncthreads();
    // Rs[i][n] = dco[i] * sum_j VT[i][j]*Ab[j][n], 4 n per task
    for (int idx = tid; idx < 4000; idx += 256){
        int i = idx/50, n0 = (idx%50)*4;
        float d = cs[i];
        const float* vrow = VT + i*82;
        float4 a; a.x = a.y = a.z = a.w = 0.f;
        for (int j = 0; j < 80; j++){
            float vv = vrow[j];
            const float4 ab = *(const float4*)&Ab[j*200 + n0];
            a.x += vv*ab.x; a.y += vv*ab.y; a.z += vv*ab.z; a.w += vv*ab.w;
        }
        a.x *= d; a.y *= d; a.z *= d; a.w *= d;
        *(float4*)&W[OFF_RS + b*16000 + i*200 + n0] = a;
    }
}

// ---------------- tv = upper-tri(Rs^T Rs + logc*I) ----------------
__global__ void ktv(float* __restrict__ W)
{
    __shared__ float rsn[80];
    int bid = blockIdx.x, tid = threadIdx.x;
    int b = bid/200, n = bid%200;
    for (int i = tid; i < 80; i += 64) rsn[i] = W[OFF_RS + b*16000 + i*200 + n];
    __syncthreads();
    long tb = OFF_TV + (long)b*20100 + (long)n*200 - (long)n*(n-1)/2;
    for (int m = n + tid; m < 200; m += 64){
        float a = 0.f;
        for (int i = 0; i < 80; i++) a += rsn[i]*W[OFF_RS + b*16000 + i*200 + m];
        if (m == n) a += LOGC;
        W[tb + (m-n)] = a;
    }
}

// ---------------- tn1 linear 20100->256 (block per output r, all batches) ----------------
__global__ void __launch_bounds__(256) ktn1(const float* __restrict__ w, const float* __restrict__ bias,
                                            float* __restrict__ W)
{
    __shared__ float part[4][16];
    int r = blockIdx.x, tid = threadIdx.x, lane = tid & 63, wv = tid >> 6;
    float acc[16];
    #pragma unroll
    for (int i = 0; i < 16; i++) acc[i] = 0.f;
    for (int vj = tid; vj < 20100; vj += 256){
        float wvv = w[(long)r*20100 + vj];
        #pragma unroll
        for (int bb = 0; bb < 16; bb++) acc[bb] += wvv * W[OFF_TV + (long)bb*20100 + vj];
    }
    #pragma unroll
    for (int bb = 0; bb < 16; bb++) acc[bb] = wsum(acc[bb]);
    if (lane == 0){
        #pragma unroll
        for (int bb = 0; bb < 16; bb++) part[wv][bb] = acc[bb];
    }
    __syncthreads();
    if (tid < 16){
        float s = part[0][tid]+part[1][tid]+part[2][tid]+part[3][tid] + bias[r];
        W[OFF_TN1O + tid*256 + r] = s;
    }
}

// ---------------- head: tn2 + concat + cls/site (one block per batch) ----------------
__global__ void __launch_bounds__(256) khead(const float* __restrict__ tn2w, const float* __restrict__ tn2b,
                      const float* __restrict__ cl1w, const float* __restrict__ cl1b,
                      const float* __restrict__ cl2w, const float* __restrict__ cl2b,
                      const float* __restrict__ sc1w, const float* __restrict__ sc1b,
                      const float* __restrict__ sc2w, const float* __restrict__ sc2b,
                      const float* __restrict__ W, float* __restrict__ out)
{
    __shared__ float g[256], feats[128], h1[64], h2[32];
    int b = blockIdx.x, tid = threadIdx.x;
    float v = W[OFF_TN1O + b*256 + tid] * BN_SC;
    g[tid] = v > 0.f ? v : 0.1f*v;
    if (tid < 64) feats[tid] = W[OFF_FEATST + b*64 + tid];
    __syncthreads();
    {   // tn2: 64 outputs x 4-lane split
        int o = tid >> 2, s3 = tid & 3;
        const float* wrow = tn2w + o*256 + s3*64;
        const float* grow = g + s3*64;
        float acc = 0.f;
        #pragma unroll 8
        for (int e = 0; e < 64; e++) acc += wrow[e]*grow[e];
        acc += __shfl_xor(acc, 1);
        acc += __shfl_xor(acc, 2);
        if (s3 == 0) feats[64+o] = fmaxf(acc + tn2b[o], 0.f);
    }
    __syncthreads();
    if (tid < 64){
        float a = cl1b[tid];
        #pragma unroll 8
        for (int k = 0; k < 128; k++) a += cl1w[tid*128+k]*feats[k];
        h1[tid] = fmaxf(a, 0.f);
    } else if (tid < 96){
        int i = tid-64;
        float a = sc1b[i];
        #pragma unroll 8
        for (int k = 0; k < 128; k++) a += sc1w[i*128+k]*feats[k];
        h2[i] = fmaxf(a, 0.f);
    }
    __syncthreads();
    if (tid < 2){
        float a = cl2b[tid];
        for (int i = 0; i < 64; i++) a += cl2w[tid*64+i]*h1[i];
        out[b*2+tid] = a;
    } else if (tid >= 32 && tid < 49){
        int o = tid-32;
        float a = sc2b[o];
        for (int i = 0; i < 32; i++) a += sc2w[o*32+i]*h2[i];
        out[32 + b*17 + o] = a;
    }
}

extern "C" void kernel_launch(void* const* d_in, const int* in_sizes, int n_in,
                              void* d_out, int out_size, void* d_ws, size_t ws_size,
                              hipStream_t stream)
{
    const float* x     = (const float*)d_in[0];
    const float* adj   = (const float*)d_in[1];
    const float* g1W   = (const float*)d_in[2];
    const float* g1a   = (const float*)d_in[3];
    const float* b1c3w = (const float*)d_in[4];
    const float* b1c3b = (const float*)d_in[5];
    const float* b1c5w = (const float*)d_in[6];
    const float* b1c5b = (const float*)d_in[7];
    const float* b1c7w = (const float*)d_in[8];
    const float* b1c7b = (const float*)d_in[9];
    const float* b1fw  = (const float*)d_in[10];
    const float* b1fb  = (const float*)d_in[11];
    const float* g2W   = (const float*)d_in[12];
    const float* g2a   = (const float*)d_in[13];
    const float* b2c3w = (const float*)d_in[14];
    const float* b2c3b = (const float*)d_in[15];
    const float* b2c5w = (const float*)d_in[16];
    const float* b2c5b = (const float*)d_in[17];
    const float* b2c7w = (const float*)d_in[18];
    const float* b2c7b = (const float*)d_in[19];
    const float* b2fw  = (const float*)d_in[20];
    const float* b2fb  = (const float*)d_in[21];
    const float* fbw   = (const float*)d_in[22];
    const float* fbb   = (const float*)d_in[23];
    const float* spw   = (const float*)d_in[24];
    const float* spb   = (const float*)d_in[25];
    const float* ainw  = (const float*)d_in[26];
    const float* ainb  = (const float*)d_in[27];
    const float* aow   = (const float*)d_in[28];
    const float* aob   = (const float*)d_in[29];
    const float* ln1g  = (const float*)d_in[30];
    const float* ln1b  = (const float*)d_in[31];
    const float* ln2g  = (const float*)d_in[32];
    const float* ln2b  = (const float*)d_in[33];
    const float* ff1w  = (const float*)d_in[34];
    const float* ff1b  = (const float*)d_in[35];
    const float* ff2w  = (const float*)d_in[36];
    const float* ff2b  = (const float*)d_in[37];
    const float* tn1w  = (const float*)d_in[38];
    const float* tn1b  = (const float*)d_in[39];
    const float* tn2w  = (const float*)d_in[40];
    const float* tn2b  = (const float*)d_in[41];
    const float* cl1w  = (const float*)d_in[42];
    const float* cl1b  = (const float*)d_in[43];
    const float* cl2w  = (const float*)d_in[44];
    const float* cl2b  = (const float*)d_in[45];
    const float* sc1w  = (const float*)d_in[46];
    const float* sc1b  = (const float*)d_in[47];
    const float* sc2w  = (const float*)d_in[48];
    const float* sc2b  = (const float*)d_in[49];
    float* W = (float*)d_ws;
    float* out = (float*)d_out;

    kprep1<<<128, 256, 0, stream>>>(spw, b2fw, b2c3w, b2c5w, b2c7w, b2c3b, b2c5b, b2c7b, b2fb, W);
    kprep2<<<1, 256, 0, stream>>>(g1W, g1a, b1c3w, b1c5w, b1c7w, b1c3b, b1c5b, b1c7b, b1fw, b1fb,
                                  adj, ainw, aow, ff1w, ff2w, W);
    kgat1<<<1280, 256, 0, stream>>>(x, W);
    kgat2<<<1280, 256, 109056, stream>>>(g2W, g2a, W);
    kconv2fb<<<1600, 256, 48512, stream>>>(fbw, fbb, W);
    ksp<<<1280, 256, 0, stream>>>(spb, W);
    kattn<<<16, 256, 104640, stream>>>(ainb, aob, ln1g, ln1b, ln2g, ln2b, ff1b, ff2b, W);
    kgram<<<16, 256, 64000, stream>>>(x, W);
    kjacobi<<<16, 256, 116544, stream>>>(W);
    ktv<<<3200, 64, 0, stream>>>(W);
    ktn1<<<256, 256, 0, stream>>>(tn1w, tn1b, W);
    khead<<<16, 256, 0, stream>>>(tn2w, tn2b, cl1w, cl1b, cl2w, cl2b, sc1w, sc1b, sc2w, sc2b, W, out);
}